// Round 1
// baseline (372.313 us; speedup 1.0000x reference)
//
#include <hip/hip_runtime.h>
#include <hip/hip_bf16.h>
#include <stdint.h>

// dist[i,j] = ||s_i||^2 + ||t_j||^2 - 2 s_i . t_j
// Strategy: prep kernels cast s -> bf16(-2*s), t -> bf16(t) into d_ws and
// compute exact f32 row norms; then an m97-style 128x128 bf16 MFMA GEMM with
// global_load_lds width=16 staging computes cross and fuses the epilogue.

typedef __attribute__((ext_vector_type(8))) short short8v;   // 8 bf16 (4 VGPRs)
typedef __attribute__((ext_vector_type(4))) float f32x4;     // 4 fp32 acc

static __device__ __forceinline__ unsigned short f32_to_bf16_rne(float f) {
    unsigned int u = __float_as_uint(f);
    unsigned int lsb = (u >> 16) & 1u;
    u += 0x7fffu + lsb;
    return (unsigned short)(u >> 16);
}

static __device__ __forceinline__ void async_load16(const void* g, void* l) {
    __builtin_amdgcn_global_load_lds(
        (const __attribute__((address_space(1))) void*)g,
        (__attribute__((address_space(3))) void*)l,
        16, 0, 0);
}

// One wave per row (D must be 512): 8 f32/lane, norm + scaled bf16 conversion.
__global__ __launch_bounds__(256) void prep_kernel(const float* __restrict__ x,
                                                   unsigned short* __restrict__ xb,
                                                   float* __restrict__ nrm,
                                                   float scale) {
    const int tid  = threadIdx.x;
    const int wid  = tid >> 6;
    const int lane = tid & 63;
    const int row  = blockIdx.x * 4 + wid;
    const float* xr = x + (size_t)row * 512;

    float4 v0 = ((const float4*)xr)[lane * 2 + 0];
    float4 v1 = ((const float4*)xr)[lane * 2 + 1];

    float ss = v0.x * v0.x + v0.y * v0.y + v0.z * v0.z + v0.w * v0.w
             + v1.x * v1.x + v1.y * v1.y + v1.z * v1.z + v1.w * v1.w;
#pragma unroll
    for (int off = 32; off > 0; off >>= 1) ss += __shfl_down(ss, off, 64);
    if (lane == 0) nrm[row] = ss;

    unsigned short u[8];
    float vals[8] = {v0.x, v0.y, v0.z, v0.w, v1.x, v1.y, v1.z, v1.w};
#pragma unroll
    for (int e = 0; e < 8; ++e) u[e] = f32_to_bf16_rne(vals[e] * scale);
    unsigned int w0 = (unsigned)u[0] | ((unsigned)u[1] << 16);
    unsigned int w1 = (unsigned)u[2] | ((unsigned)u[3] << 16);
    unsigned int w2 = (unsigned)u[4] | ((unsigned)u[5] << 16);
    unsigned int w3 = (unsigned)u[6] | ((unsigned)u[7] << 16);
    uint4 pk = make_uint4(w0, w1, w2, w3);
    ((uint4*)(xb + (size_t)row * 512))[lane] = pk;
}

#define TILE 128
#define BK 32

// sb holds bf16(-2*s)  [N][D];  tb holds bf16(t)  [Q][D] (i.e. B^T layout).
// out[i*Q+j] = ssq[i] + tsq[j] + sum_k sb[i][k]*tb[j][k]
__global__ __launch_bounds__(256) void dist_mfma(const unsigned short* __restrict__ sb,
                                                 const unsigned short* __restrict__ tb,
                                                 const float* __restrict__ ssq,
                                                 const float* __restrict__ tsq,
                                                 float* __restrict__ out,
                                                 int N, int Q, int D) {
    __shared__ unsigned short lds_a[TILE * BK];
    __shared__ unsigned short lds_b[TILE * BK];

    const int tid  = threadIdx.x;
    const int wid  = tid >> 6;
    const int lane = tid & 63;
    const int quad = lane >> 4;
    const int r    = lane & 15;

    // block -> (bm,bn) with 8x8 supertile swizzle for L2 locality
    const int bid = blockIdx.x;
    const int nBm = N / TILE, nBn = Q / TILE;
    int bm, bn;
    if ((nBm & 7) == 0 && (nBn & 7) == 0) {
        const int super = bid >> 6, within = bid & 63;
        const int spr = nBn >> 3;
        const int sm = super / spr, sn = super % spr;
        bm = (sm << 3) + (within >> 3);
        bn = (sn << 3) + (within & 7);
    } else {
        bm = bid / nBn;
        bn = bid - bm * nBn;
    }

    const int m_w = (wid & 1) * 64;   // wave's m offset in tile
    const int n_w = (wid >> 1) * 64;  // wave's n offset in tile

    f32x4 acc[4][4];
#pragma unroll
    for (int a = 0; a < 4; ++a)
#pragma unroll
        for (int b = 0; b < 4; ++b) acc[a][b] = (f32x4){0.f, 0.f, 0.f, 0.f};

    // staging: 256 threads x 16B chunks; chunk c covers tile row c>>2, k-bytes (c&3)*16
    const int c    = tid;
    const int srow = c >> 2;
    const int skb  = (c & 3) << 3;  // element offset in k
    const unsigned short* gA = sb + (size_t)(bm * TILE + srow) * D + skb;
    const unsigned short* gB = tb + (size_t)(bn * TILE + srow) * D + skb;
    unsigned short* lA = lds_a + wid * 512;  // wave-uniform base; HW adds lane*16B
    unsigned short* lB = lds_b + wid * 512;
    const size_t half_g = (size_t)64 * D;    // rows 64..127

    for (int k0 = 0; k0 < D; k0 += BK) {
        __syncthreads();
        async_load16(gA + k0,          lA);
        async_load16(gA + k0 + half_g, lA + 2048);
        async_load16(gB + k0,          lB);
        async_load16(gB + k0 + half_g, lB + 2048);
        __syncthreads();

        short8v aF[4], bF[4];
#pragma unroll
        for (int im = 0; im < 4; ++im)
            aF[im] = *(const short8v*)(lds_a + (m_w + im * 16 + r) * BK + quad * 8);
#pragma unroll
        for (int in = 0; in < 4; ++in)
            bF[in] = *(const short8v*)(lds_b + (n_w + in * 16 + r) * BK + quad * 8);
#pragma unroll
        for (int im = 0; im < 4; ++im)
#pragma unroll
            for (int in = 0; in < 4; ++in)
                acc[im][in] = __builtin_amdgcn_mfma_f32_16x16x32_bf16(
                    aF[im], bF[in], acc[im][in], 0, 0, 0);
    }

    // epilogue: C/D layout col = lane&15, row = quad*4 + reg
    const int gm = bm * TILE + m_w;
    const int gn = bn * TILE + n_w;
    float tq[4];
#pragma unroll
    for (int in = 0; in < 4; ++in) tq[in] = tsq[gn + in * 16 + r];
#pragma unroll
    for (int im = 0; im < 4; ++im) {
#pragma unroll
        for (int j = 0; j < 4; ++j) {
            const int i = gm + im * 16 + quad * 4 + j;
            const float sv = ssq[i];
            float* orow = out + (size_t)i * (size_t)Q + gn;
#pragma unroll
            for (int in = 0; in < 4; ++in)
                orow[in * 16 + r] = sv + tq[in] + acc[im][in][j];
        }
    }
}

// Correctness fallback if d_ws is too small for the bf16 copies.
__global__ void dist_fallback(const float* __restrict__ s, const float* __restrict__ t,
                              float* __restrict__ out, int N, int Q, int D) {
    __shared__ float ls[16][17], lt[16][17];
    const int tj = threadIdx.x, ti = threadIdx.y;
    const int i = blockIdx.y * 16 + ti, j = blockIdx.x * 16 + tj;
    float cross = 0.f, ssq = 0.f, tsq = 0.f;
    for (int k0 = 0; k0 < D; k0 += 16) {
        __syncthreads();
        ls[ti][tj] = s[(size_t)(blockIdx.y * 16 + ti) * D + k0 + tj];
        lt[ti][tj] = t[(size_t)(blockIdx.x * 16 + ti) * D + k0 + tj];
        __syncthreads();
#pragma unroll
        for (int kk = 0; kk < 16; ++kk) {
            float a = ls[ti][kk], b = lt[tj][kk];
            cross += a * b; ssq += a * a; tsq += b * b;
        }
    }
    out[(size_t)i * Q + j] = ssq + tsq - 2.f * cross;
}

extern "C" void kernel_launch(void* const* d_in, const int* in_sizes, int n_in,
                              void* d_out, int out_size, void* d_ws, size_t ws_size,
                              hipStream_t stream) {
    const float* s = (const float*)d_in[0];
    const float* t = (const float*)d_in[1];
    float* out = (float*)d_out;
    const int D = 512;
    const int N = in_sizes[0] / D;  // 8192
    const int Q = in_sizes[1] / D;  // 8192

    const size_t need = ((size_t)N + (size_t)Q) * D * sizeof(unsigned short)
                      + ((size_t)N + (size_t)Q) * sizeof(float);

    if (ws_size >= need && D == 512 && (N % TILE) == 0 && (Q % TILE) == 0) {
        unsigned short* sb = (unsigned short*)d_ws;
        unsigned short* tb = sb + (size_t)N * D;
        float* ssq = (float*)(tb + (size_t)Q * D);
        float* tsq = ssq + N;
        prep_kernel<<<N / 4, 256, 0, stream>>>(s, sb, ssq, -2.0f);
        prep_kernel<<<Q / 4, 256, 0, stream>>>(t, tb, tsq, 1.0f);
        const int blocks = (N / TILE) * (Q / TILE);
        dist_mfma<<<blocks, 256, 0, stream>>>(sb, tb, ssq, tsq, out, N, Q, D);
    } else {
        dim3 g(Q / 16, N / 16), b(16, 16);
        dist_fallback<<<g, b, 0, stream>>>(s, t, out, N, Q, D);
    }
}

// Round 2
// 349.833 us; speedup vs baseline: 1.0643x; 1.0643x over previous
//
#include <hip/hip_runtime.h>
#include <hip/hip_bf16.h>
#include <stdint.h>

// dist[i,j] = ||s_i||^2 + ||t_j||^2 - 2 s_i . t_j
// prep: s -> bf16(-2*s), t -> bf16(t) into d_ws + exact f32 row norms.
// main: 128x128 bf16 MFMA GEMM, BK=64, global_load_lds width=16 staging with
// 16B-chunk XOR swizzle (conflict-free ds_read_b128), fused epilogue with
// nontemporal stores.

typedef __attribute__((ext_vector_type(8))) short short8v;   // 8 bf16 (4 VGPRs)
typedef __attribute__((ext_vector_type(4))) float f32x4;     // 4 fp32 acc

static __device__ __forceinline__ unsigned short f32_to_bf16_rne(float f) {
    unsigned int u = __float_as_uint(f);
    unsigned int lsb = (u >> 16) & 1u;
    u += 0x7fffu + lsb;
    return (unsigned short)(u >> 16);
}

static __device__ __forceinline__ void async_load16(const void* g, void* l) {
    __builtin_amdgcn_global_load_lds(
        (const __attribute__((address_space(1))) void*)g,
        (__attribute__((address_space(3))) void*)l,
        16, 0, 0);
}

// One wave per row (D must be 512): 8 f32/lane, norm + scaled bf16 conversion.
__global__ __launch_bounds__(256) void prep_kernel(const float* __restrict__ x,
                                                   unsigned short* __restrict__ xb,
                                                   float* __restrict__ nrm,
                                                   float scale) {
    const int tid  = threadIdx.x;
    const int wid  = tid >> 6;
    const int lane = tid & 63;
    const int row  = blockIdx.x * 4 + wid;
    const float* xr = x + (size_t)row * 512;

    float4 v0 = ((const float4*)xr)[lane * 2 + 0];
    float4 v1 = ((const float4*)xr)[lane * 2 + 1];

    float ss = v0.x * v0.x + v0.y * v0.y + v0.z * v0.z + v0.w * v0.w
             + v1.x * v1.x + v1.y * v1.y + v1.z * v1.z + v1.w * v1.w;
#pragma unroll
    for (int off = 32; off > 0; off >>= 1) ss += __shfl_down(ss, off, 64);
    if (lane == 0) nrm[row] = ss;

    unsigned short u[8];
    float vals[8] = {v0.x, v0.y, v0.z, v0.w, v1.x, v1.y, v1.z, v1.w};
#pragma unroll
    for (int e = 0; e < 8; ++e) u[e] = f32_to_bf16_rne(vals[e] * scale);
    unsigned int w0 = (unsigned)u[0] | ((unsigned)u[1] << 16);
    unsigned int w1 = (unsigned)u[2] | ((unsigned)u[3] << 16);
    unsigned int w2 = (unsigned)u[4] | ((unsigned)u[5] << 16);
    unsigned int w3 = (unsigned)u[6] | ((unsigned)u[7] << 16);
    uint4 pk = make_uint4(w0, w1, w2, w3);
    ((uint4*)(xb + (size_t)row * 512))[lane] = pk;
}

#define TILE 128
#define BK 64
// BK=64: 8 K-iterations (vs 16), 32 MFMA per barrier drain. LDS = 2*16 KB.
// 16B-chunk XOR swizzle: LDS slot (row, c) holds global chunk c ^ (row&7).
// Staging stays lane-contiguous (global_load_lds requirement, m104/m108);
// ds_read_b128 fragment reads spread across all 32 banks (2-way = free).

__global__ __launch_bounds__(256) void dist_mfma(const unsigned short* __restrict__ sb,
                                                 const unsigned short* __restrict__ tb,
                                                 const float* __restrict__ ssq,
                                                 const float* __restrict__ tsq,
                                                 float* __restrict__ out,
                                                 int N, int Q, int D) {
    __shared__ unsigned short lds_a[TILE * BK];
    __shared__ unsigned short lds_b[TILE * BK];

    const int tid  = threadIdx.x;
    const int wid  = tid >> 6;
    const int lane = tid & 63;
    const int quad = lane >> 4;
    const int r    = lane & 15;

    // block -> (bm,bn) with 8x8 supertile swizzle for L2 locality
    const int bid = blockIdx.x;
    const int nBm = N / TILE, nBn = Q / TILE;
    int bm, bn;
    if ((nBm & 7) == 0 && (nBn & 7) == 0) {
        const int super = bid >> 6, within = bid & 63;
        const int spr = nBn >> 3;
        const int sm = super / spr, sn = super % spr;
        bm = (sm << 3) + (within >> 3);
        bn = (sn << 3) + (within & 7);
    } else {
        bm = bid / nBn;
        bn = bid - bm * nBn;
    }

    const int m_w = (wid & 1) * 64;   // wave's m offset in tile
    const int n_w = (wid >> 1) * 64;  // wave's n offset in tile

    f32x4 acc[4][4];
#pragma unroll
    for (int a = 0; a < 4; ++a)
#pragma unroll
        for (int b = 0; b < 4; ++b) acc[a][b] = (f32x4){0.f, 0.f, 0.f, 0.f};

    // Staging precompute: 4 insts/matrix/iter; inst i, thread tid covers LDS
    // 16B-chunk p = i*256+tid -> row p>>3, slot p&7 -> global chunk
    // (p&7)^(row&7). Per-wave LDS dest base is uniform (lane-contiguous 1 KB).
    const unsigned short* gA[4];
    const unsigned short* gB[4];
    unsigned short* lA[4];
    unsigned short* lB[4];
#pragma unroll
    for (int i = 0; i < 4; ++i) {
        const int p    = i * 256 + tid;
        const int row  = p >> 3;
        const int gch  = (tid & 7) ^ (row & 7);
        gA[i] = sb + (size_t)(bm * TILE + row) * D + gch * 8;
        gB[i] = tb + (size_t)(bn * TILE + row) * D + gch * 8;
        lA[i] = lds_a + (i * 256 + wid * 64) * 8;
        lB[i] = lds_b + (i * 256 + wid * 64) * 8;
    }

    for (int k0 = 0; k0 < D; k0 += BK) {
        __syncthreads();
#pragma unroll
        for (int i = 0; i < 4; ++i) {
            async_load16(gA[i] + k0, lA[i]);
            async_load16(gB[i] + k0, lB[i]);
        }
        __syncthreads();

#pragma unroll
        for (int ks = 0; ks < 2; ++ks) {
            short8v aF[4], bF[4];
#pragma unroll
            for (int im = 0; im < 4; ++im) {
                const int row = m_w + im * 16 + r;
                const int cp  = (ks * 4 + quad) ^ (row & 7);
                aF[im] = *(const short8v*)(lds_a + row * BK + cp * 8);
            }
#pragma unroll
            for (int in = 0; in < 4; ++in) {
                const int row = n_w + in * 16 + r;
                const int cp  = (ks * 4 + quad) ^ (row & 7);
                bF[in] = *(const short8v*)(lds_b + row * BK + cp * 8);
            }
#pragma unroll
            for (int im = 0; im < 4; ++im)
#pragma unroll
                for (int in = 0; in < 4; ++in)
                    acc[im][in] = __builtin_amdgcn_mfma_f32_16x16x32_bf16(
                        aF[im], bF[in], acc[im][in], 0, 0, 0);
        }
    }

    // epilogue: C/D layout col = lane&15, row = quad*4 + reg. Nontemporal
    // stores: keep the (L2-resident) bf16 inputs from being evicted by the
    // 268 MB output stream.
    const int gm = bm * TILE + m_w;
    const int gn = bn * TILE + n_w;
    float tq[4];
#pragma unroll
    for (int in = 0; in < 4; ++in) tq[in] = tsq[gn + in * 16 + r];
#pragma unroll
    for (int im = 0; im < 4; ++im) {
#pragma unroll
        for (int j = 0; j < 4; ++j) {
            const int i = gm + im * 16 + quad * 4 + j;
            const float sv = ssq[i];
            float* orow = out + (size_t)i * (size_t)Q + gn;
#pragma unroll
            for (int in = 0; in < 4; ++in)
                __builtin_nontemporal_store(sv + tq[in] + acc[im][in][j],
                                            &orow[in * 16 + r]);
        }
    }
}

// Correctness fallback if d_ws is too small for the bf16 copies.
__global__ void dist_fallback(const float* __restrict__ s, const float* __restrict__ t,
                              float* __restrict__ out, int N, int Q, int D) {
    __shared__ float ls[16][17], lt[16][17];
    const int tj = threadIdx.x, ti = threadIdx.y;
    const int i = blockIdx.y * 16 + ti, j = blockIdx.x * 16 + tj;
    float cross = 0.f, ssq = 0.f, tsq = 0.f;
    for (int k0 = 0; k0 < D; k0 += 16) {
        __syncthreads();
        ls[ti][tj] = s[(size_t)(blockIdx.y * 16 + ti) * D + k0 + tj];
        lt[ti][tj] = t[(size_t)(blockIdx.x * 16 + ti) * D + k0 + tj];
        __syncthreads();
#pragma unroll
        for (int kk = 0; kk < 16; ++kk) {
            float a = ls[ti][kk], b = lt[tj][kk];
            cross += a * b; ssq += a * a; tsq += b * b;
        }
    }
    out[(size_t)i * Q + j] = ssq + tsq - 2.f * cross;
}

extern "C" void kernel_launch(void* const* d_in, const int* in_sizes, int n_in,
                              void* d_out, int out_size, void* d_ws, size_t ws_size,
                              hipStream_t stream) {
    const float* s = (const float*)d_in[0];
    const float* t = (const float*)d_in[1];
    float* out = (float*)d_out;
    const int D = 512;
    const int N = in_sizes[0] / D;  // 8192
    const int Q = in_sizes[1] / D;  // 8192

    const size_t need = ((size_t)N + (size_t)Q) * D * sizeof(unsigned short)
                      + ((size_t)N + (size_t)Q) * sizeof(float);

    if (ws_size >= need && D == 512 && (N % TILE) == 0 && (Q % TILE) == 0) {
        unsigned short* sb = (unsigned short*)d_ws;
        unsigned short* tb = sb + (size_t)N * D;
        float* ssq = (float*)(tb + (size_t)Q * D);
        float* tsq = ssq + N;
        prep_kernel<<<N / 4, 256, 0, stream>>>(s, sb, ssq, -2.0f);
        prep_kernel<<<Q / 4, 256, 0, stream>>>(t, tb, tsq, 1.0f);
        const int blocks = (N / TILE) * (Q / TILE);
        dist_mfma<<<blocks, 256, 0, stream>>>(sb, tb, ssq, tsq, out, N, Q, D);
    } else {
        dim3 g(Q / 16, N / 16), b(16, 16);
        dist_fallback<<<g, b, 0, stream>>>(s, t, out, N, Q, D);
    }
}